// Round 8
// baseline (11616.301 us; speedup 1.0000x reference)
//
#include <hip/hip_runtime.h>
#include <math.h>

// Problem dims
#define TT 2048
#define VV 1024
#define HH 2048
#define SS (VV + HH)        // 3072: row stride of Wf_w / Wb_w

// Geometry: 256 WGs x 512 threads, one WG per CU (forced by ~137KB LDS).
#define NWGD 128            // workgroups per direction
#define BTH  512            // threads per workgroup (8 waves = 2/EU)
#define UPW  16             // hidden units per wg (= rowgroups)
#define KSL  32             // k-slices per row (lanes per rowgroup)
#define KPT  64             // k-elements per thread per row
#define CHR  16             // float4 chunks per row per thread (KPT/4)
#define RCHR 12             // chunks per row in VGPRs (4 gates x 12 -> 192 regs)
#define LCHR 4              // chunks per row in LDS (4 x 4 x 16B x 512 thr = 128KB)

static_assert(NWGD * UPW == HH, "unit coverage");
static_assert(UPW * KSL == BTH, "thread coverage");
static_assert(KSL * KPT == HH, "k coverage");
static_assert(RCHR + LCHR == CHR, "chunk split");

__device__ __forceinline__ float sigmoidf_(float x) {
    return 1.0f / (1.0f + __expf(-x));
}

// Mailbox: mb[dir][parity][unit] : u64 = (tag<<32) | float_bits(h).
// Data + validity in ONE 8B store -> one L3 visibility latency per step.

__global__ __launch_bounds__(BTH) __attribute__((amdgpu_waves_per_eu(2, 2)))
void lstm_kernel(const float* __restrict__ Wf, const float* __restrict__ bfv,
                 const float* __restrict__ Wb, const float* __restrict__ bbv,
                 const int* __restrict__ cidx,
                 float* __restrict__ hsf, float* __restrict__ hsb,
                 unsigned long long* __restrict__ mb)
{
    const int wg   = blockIdx.x;
    const int dir  = wg >> 7;            // 0 fwd, 1 bwd
    const int w    = wg & (NWGD - 1);
    const int tid  = threadIdx.x;
    const int rg   = tid >> 5;           // unit_local 0..15
    const int ks   = tid & (KSL - 1);    // k-slice 0..31
    const int unit = w * UPW + rg;

    const float* W    = dir ? Wb : Wf;
    const float* bias = dir ? bbv : bfv;
    float* hs         = dir ? hsb : hsf;
    unsigned long long* mbd = mb + (size_t)dir * 2 * HH;   // [parity][unit]

    // LDS: weights [gate*LCHR + c][tid] float4 (lane-sequential, conflict-free),
    // h padded so slice starts hit distinct bank groups (float4 idx 17*ks).
    __shared__ float4 wl4[4 * LCHR * BTH];                // 128 KB
    __shared__ float4 hl4[(HH + 4 * (HH / 64)) / 4];      // 544 float4 = 8.5 KB

    // ---- one-time: weight slab -> VGPRs (pinned) + LDS ----
    float4 wr[4][RCHR];
    #pragma unroll
    for (int j = 0; j < 4; ++j) {
        const float* rbase = W + (size_t)(j * HH + unit) * SS + VV + ks * KPT;
        #pragma unroll
        for (int c = 0; c < RCHR; ++c)
            wr[j][c] = *reinterpret_cast<const float4*>(rbase + 4 * c);
        #pragma unroll
        for (int c = 0; c < LCHR; ++c)
            wl4[(j * LCHR + c) * BTH + tid] =
                *reinterpret_cast<const float4*>(rbase + 4 * (RCHR + c));
    }
    // Pin: make the 48 float4 opaque so the compiler can neither spill-cheaply
    // nor REMATERIALIZE them from global memory inside the t-loop.
    #pragma unroll
    for (int j = 0; j < 4; ++j)
        #pragma unroll
        for (int c = 0; c < RCHR; ++c)
            asm volatile("" : "+v"(wr[j][c].x), "+v"(wr[j][c].y),
                              "+v"(wr[j][c].z), "+v"(wr[j][c].w));

    const float b_i = bias[0 * HH + unit];
    const float b_f = bias[1 * HH + unit];
    const float b_g = bias[2 * HH + unit];
    const float b_o = bias[3 * HH + unit];
    float creg = 0.0f;                                    // cell state (lane ks==0)

    // prestage h=0 for step 0
    hl4[tid + (tid >> 4)] = make_float4(0.f, 0.f, 0.f, 0.f);
    __syncthreads();

    for (int s = 0; s < TT; ++s) {
        const int t  = dir ? (TT - 1 - s) : s;
        const int xt = cidx[t];
        // one-hot gather for this unit's 4 gate rows (exact fp32, L2/L3-hot)
        float gx0 = 0.f, gx1 = 0.f, gx2 = 0.f, gx3 = 0.f;
        if (ks == 0) {
            gx0 = W[(size_t)(0 * HH + unit) * SS + xt];
            gx1 = W[(size_t)(1 * HH + unit) * SS + xt];
            gx2 = W[(size_t)(2 * HH + unit) * SS + xt];
            gx3 = W[(size_t)(3 * HH + unit) * SS + xt];
        }

        // ---- recurrent dot: 4 gate rows x 64 k; each h-read feeds 16 FMAs ----
        float a0 = 0.f, a1 = 0.f, a2 = 0.f, a3 = 0.f;
        const int hb = 17 * ks;                           // padded float4 base
        #pragma unroll
        for (int c = 0; c < CHR; ++c) {
            const float4 hv = hl4[hb + c];
            float4 w0, w1, w2, w3;
            if (c < RCHR) {
                w0 = wr[0][c]; w1 = wr[1][c]; w2 = wr[2][c]; w3 = wr[3][c];
            } else {
                w0 = wl4[(0 * LCHR + (c - RCHR)) * BTH + tid];
                w1 = wl4[(1 * LCHR + (c - RCHR)) * BTH + tid];
                w2 = wl4[(2 * LCHR + (c - RCHR)) * BTH + tid];
                w3 = wl4[(3 * LCHR + (c - RCHR)) * BTH + tid];
            }
            a0 = fmaf(w0.x, hv.x, a0); a0 = fmaf(w0.y, hv.y, a0);
            a0 = fmaf(w0.z, hv.z, a0); a0 = fmaf(w0.w, hv.w, a0);
            a1 = fmaf(w1.x, hv.x, a1); a1 = fmaf(w1.y, hv.y, a1);
            a1 = fmaf(w1.z, hv.z, a1); a1 = fmaf(w1.w, hv.w, a1);
            a2 = fmaf(w2.x, hv.x, a2); a2 = fmaf(w2.y, hv.y, a2);
            a2 = fmaf(w2.z, hv.z, a2); a2 = fmaf(w2.w, hv.w, a2);
            a3 = fmaf(w3.x, hv.x, a3); a3 = fmaf(w3.y, hv.y, a3);
            a3 = fmaf(w3.z, hv.z, a3); a3 = fmaf(w3.w, hv.w, a3);
        }
        // butterfly over the 32 k-slices (xor<=16 stays within each 32-half)
        #pragma unroll
        for (int off = 1; off < KSL; off <<= 1) {
            a0 += __shfl_xor(a0, off, 64);
            a1 += __shfl_xor(a1, off, 64);
            a2 += __shfl_xor(a2, off, 64);
            a3 += __shfl_xor(a3, off, 64);
        }

        // ---- LSTM cell in-lane (ks==0); publish = ONE u64 atomic store ----
        if (ks == 0) {
            const float gi = sigmoidf_(a0 + gx0 + b_i);
            const float gf = sigmoidf_(a1 + gx1 + b_f);
            const float gg = tanhf(a2 + gx2 + b_g);
            const float go = sigmoidf_(a3 + gx3 + b_o);
            creg = gf * creg + gi * gg;
            const float hv = go * tanhf(creg);
            const unsigned long long pv =
                ((unsigned long long)(unsigned)(s + 1) << 32) | __float_as_uint(hv);
            __hip_atomic_store(mbd + (size_t)(s & 1) * HH + unit, pv,
                               __ATOMIC_RELAXED, __HIP_MEMORY_SCOPE_AGENT);
            hs[(size_t)t * HH + unit] = hv;   // plain cached store, for out_gemm
        }

        if (s + 1 < TT) {
            __syncthreads();   // A: all dot-reads of hl4 complete

            // fused poll+stage: thread stages units 4*tid..4*tid+3 (32B of
            // mailbox, one line segment; 4 independent loads per pass).
            const unsigned tag = (unsigned)(s + 1);
            const unsigned long long* src = mbd + (size_t)(s & 1) * HH + 4 * tid;
            unsigned long long v0, v1, v2, v3;
            for (;;) {
                v0 = __hip_atomic_load(src + 0, __ATOMIC_RELAXED, __HIP_MEMORY_SCOPE_AGENT);
                v1 = __hip_atomic_load(src + 1, __ATOMIC_RELAXED, __HIP_MEMORY_SCOPE_AGENT);
                v2 = __hip_atomic_load(src + 2, __ATOMIC_RELAXED, __HIP_MEMORY_SCOPE_AGENT);
                v3 = __hip_atomic_load(src + 3, __ATOMIC_RELAXED, __HIP_MEMORY_SCOPE_AGENT);
                if (((unsigned)(v0 >> 32) == tag) & ((unsigned)(v1 >> 32) == tag) &
                    ((unsigned)(v2 >> 32) == tag) & ((unsigned)(v3 >> 32) == tag))
                    break;
                __builtin_amdgcn_s_sleep(1);
            }
            float4 hv;
            hv.x = __uint_as_float((unsigned)v0);
            hv.y = __uint_as_float((unsigned)v1);
            hv.z = __uint_as_float((unsigned)v2);
            hv.w = __uint_as_float((unsigned)v3);
            hl4[tid + (tid >> 4)] = hv;

            __syncthreads();   // B: hlds ready for next dot
        }
    }
}

// out[t,v] = sum_j merged[t,j]*Wo[v,j] + bo[v],  merged = [hf | hb], K = 4096.
__global__ __launch_bounds__(256)
void out_gemm(const float* __restrict__ hsf, const float* __restrict__ hsb,
              const float* __restrict__ Wo, const float* __restrict__ bo,
              float* __restrict__ out)
{
    const int bn = blockIdx.x;
    const int bm = blockIdx.y;
    const int tid = threadIdx.x;
    const int tx = tid & 15, ty = tid >> 4;
    const int t0 = bm * 64, v0 = bn * 64;

    __shared__ float As[32][72];
    __shared__ float Bs[32][72];

    float acc[4][4] = {};

    const int rr = tid >> 2;
    const int kc = tid & 3;

    for (int kb = 0; kb < 2 * HH; kb += 32) {
        {
            const int k = kb + kc * 8;
            const float* asrc = (k < HH) ? (hsf + (size_t)(t0 + rr) * HH + k)
                                         : (hsb + (size_t)(t0 + rr) * HH + (k - HH));
            const float4 a0 = *reinterpret_cast<const float4*>(asrc);
            const float4 a1 = *reinterpret_cast<const float4*>(asrc + 4);
            const int kk = kc * 8;
            As[kk+0][rr]=a0.x; As[kk+1][rr]=a0.y; As[kk+2][rr]=a0.z; As[kk+3][rr]=a0.w;
            As[kk+4][rr]=a1.x; As[kk+5][rr]=a1.y; As[kk+6][rr]=a1.z; As[kk+7][rr]=a1.w;
            const float* bsrc = Wo + (size_t)(v0 + rr) * (2 * HH) + k;
            const float4 b0 = *reinterpret_cast<const float4*>(bsrc);
            const float4 b1 = *reinterpret_cast<const float4*>(bsrc + 4);
            Bs[kk+0][rr]=b0.x; Bs[kk+1][rr]=b0.y; Bs[kk+2][rr]=b0.z; Bs[kk+3][rr]=b0.w;
            Bs[kk+4][rr]=b1.x; Bs[kk+5][rr]=b1.y; Bs[kk+6][rr]=b1.z; Bs[kk+7][rr]=b1.w;
        }
        __syncthreads();
        #pragma unroll 8
        for (int kk = 0; kk < 32; ++kk) {
            const float4 av = *reinterpret_cast<const float4*>(&As[kk][ty * 4]);
            const float4 bv = *reinterpret_cast<const float4*>(&Bs[kk][tx * 4]);
            const float a[4] = {av.x, av.y, av.z, av.w};
            const float b[4] = {bv.x, bv.y, bv.z, bv.w};
            #pragma unroll
            for (int i2 = 0; i2 < 4; ++i2)
                #pragma unroll
                for (int j2 = 0; j2 < 4; ++j2)
                    acc[i2][j2] = fmaf(a[i2], b[j2], acc[i2][j2]);
        }
        __syncthreads();
    }
    #pragma unroll
    for (int i2 = 0; i2 < 4; ++i2) {
        const int t = t0 + ty * 4 + i2;
        #pragma unroll
        for (int j2 = 0; j2 < 4; ++j2) {
            const int v = v0 + tx * 4 + j2;
            out[(size_t)t * VV + v] = acc[i2][j2] + bo[v];
        }
    }
}

extern "C" void kernel_launch(void* const* d_in, const int* in_sizes, int n_in,
                              void* d_out, int out_size, void* d_ws, size_t ws_size,
                              hipStream_t stream)
{
    (void)in_sizes; (void)n_in; (void)out_size; (void)ws_size;

    const float* Wf  = (const float*)d_in[0];
    const float* bfv = (const float*)d_in[1];
    const float* Wb  = (const float*)d_in[2];
    const float* bbv = (const float*)d_in[3];
    const float* Wo  = (const float*)d_in[4];
    const float* bo  = (const float*)d_in[5];
    const int*   cid = (const int*)d_in[6];
    float* out = (float*)d_out;

    unsigned char* ws = (unsigned char*)d_ws;
    unsigned long long* mbx = (unsigned long long*)ws;     // 64 KiB mailbox
    float* hsf = (float*)(ws + 65536);                     // [T][H] fp32, 16 MiB
    float* hsb = hsf + (size_t)TT * HH;                    // [T][H] fp32, 16 MiB

    // Re-zero mailbox tags every launch (ws poisoned once, never restored)
    (void)hipMemsetAsync(mbx, 0, 65536, stream);

    lstm_kernel<<<dim3(2 * NWGD), dim3(BTH), 0, stream>>>(Wf, bfv, Wb, bbv, cid,
                                                          hsf, hsb, mbx);
    out_gemm<<<dim3(VV / 64, TT / 64), dim3(256), 0, stream>>>(hsf, hsb, Wo, bo, out);
}

// Round 9
// 8982.269 us; speedup vs baseline: 1.2932x; 1.2932x over previous
//
#include <hip/hip_runtime.h>
#include <math.h>

// Problem dims
#define TT 2048
#define VV 1024
#define HH 2048
#define SS (VV + HH)        // 3072: row stride of Wf_w / Wb_w

// Geometry: 256 WGs x 512 threads, one WG per CU (forced by LDS pad).
#define NWGD 128            // workgroups per direction
#define BTH  512            // threads per workgroup (8 waves = 2/EU)
#define UPW  16             // hidden units per wg
#define KSL  32             // k-slices per unit
#define KPT  64             // k-elements per thread (per gate row)

static_assert(NWGD * UPW == HH, "unit coverage");
static_assert(UPW * KSL == BTH, "thread coverage");
static_assert(KSL * KPT == HH, "k coverage");

// Flag area (uints), per direction at bar + dir*2048: flag[p] at +p*16
#define BAR_UINTS_PER_DIR 2048

typedef _Float16 half2_t __attribute__((ext_vector_type(2)));

#if defined(__has_builtin)
#if __has_builtin(__builtin_amdgcn_fdot2)
#define FDOT2(w, h, c) __builtin_amdgcn_fdot2((w), (h), (c), false)
#endif
#endif
#ifndef FDOT2
__device__ __forceinline__ float fdot2_asm(half2_t w, half2_t h, float c) {
    float r = c;
    asm volatile("v_dot2_f32_f16 %0, %1, %2, %0" : "+v"(r) : "v"(w), "v"(h));
    return r;
}
#define FDOT2(w, h, c) fdot2_asm((w), (h), (c))
#endif

__device__ __forceinline__ float sigmoidf_(float x) {
    return 1.0f / (1.0f + __expf(-x));
}

__global__ __launch_bounds__(BTH) __attribute__((amdgpu_waves_per_eu(2, 2)))
void lstm_kernel(const float* __restrict__ Wf, const float* __restrict__ bfv,
                 const float* __restrict__ Wb, const float* __restrict__ bbv,
                 const int* __restrict__ cidx,
                 float* __restrict__ hsf, float* __restrict__ hsb,
                 unsigned* __restrict__ bar)
{
    const int wg   = blockIdx.x;
    const int dir  = wg >> 7;            // 0 fwd, 1 bwd
    const int w    = wg & (NWGD - 1);
    const int tid  = threadIdx.x;
    const int rg   = tid >> 5;           // unit_local 0..15
    const int ks   = tid & (KSL - 1);    // k-slice 0..31
    const int unit = w * UPW + rg;

    const float* W    = dir ? Wb : Wf;
    const float* bias = dir ? bbv : bfv;
    float* hs         = dir ? hsb : hsf;
    unsigned* flags   = bar + dir * BAR_UINTS_PER_DIR;   // flag[p] = flags[p*16]

    // h staged in LDS as fp32, padded (17-stride float4) -> conflict-free.
    __shared__ float4 hl4[(HH + 4 * (HH / 64)) / 4];      // 544 float4 = 8.5 KB
    // Force 1 WG/CU (all 256 WGs co-resident across 256 CUs).
    __shared__ char force_one_wg[100 * 1024];
    if (tid == 0) ((volatile char*)force_one_wg)[0] = 0;

    // ---- one-time: weight slab -> 128 packed-fp16 VGPRs (4 gates x 32 half2)
    half2_t w2[4][KPT / 2];
    #pragma unroll
    for (int j = 0; j < 4; ++j) {
        const float* rbase = W + (size_t)(j * HH + unit) * SS + VV + ks * KPT;
        #pragma unroll
        for (int q = 0; q < KPT / 4; ++q) {
            const float4 wv = *reinterpret_cast<const float4*>(rbase + 4 * q);
            w2[j][2 * q]     = half2_t{(_Float16)wv.x, (_Float16)wv.y};
            w2[j][2 * q + 1] = half2_t{(_Float16)wv.z, (_Float16)wv.w};
        }
    }
    const float b_i = bias[0 * HH + unit];
    const float b_f = bias[1 * HH + unit];
    const float b_g = bias[2 * HH + unit];
    const float b_o = bias[3 * HH + unit];
    float creg = 0.0f;                                    // cell state (ks==0)

    // prestage h=0 for step 0
    hl4[tid + (tid >> 4)] = make_float4(0.f, 0.f, 0.f, 0.f);
    __syncthreads();

    for (int s = 0; s < TT; ++s) {
        const int t  = dir ? (TT - 1 - s) : s;
        const int xt = cidx[t];
        // one-hot input projection: exact fp32 gather (ks==0 lanes only)
        float gx0 = 0.f, gx1 = 0.f, gx2 = 0.f, gx3 = 0.f;
        if (ks == 0) {
            gx0 = W[(size_t)(0 * HH + unit) * SS + xt];
            gx1 = W[(size_t)(1 * HH + unit) * SS + xt];
            gx2 = W[(size_t)(2 * HH + unit) * SS + xt];
            gx3 = W[(size_t)(3 * HH + unit) * SS + xt];
        }

        // ---- recurrent dot: 4 gates x 64 k, fp16 x fp16 -> fp32 (v_dot2) ----
        float a0 = 0.f, a1 = 0.f, a2 = 0.f, a3 = 0.f;
        const int hb = 17 * ks;                           // padded float4 base
        #pragma unroll
        for (int c = 0; c < KPT / 4; ++c) {
            const float4 hv = hl4[hb + c];
            const half2_t ha = half2_t{(_Float16)hv.x, (_Float16)hv.y};
            const half2_t hc = half2_t{(_Float16)hv.z, (_Float16)hv.w};
            a0 = FDOT2(w2[0][2 * c], ha, a0); a0 = FDOT2(w2[0][2 * c + 1], hc, a0);
            a1 = FDOT2(w2[1][2 * c], ha, a1); a1 = FDOT2(w2[1][2 * c + 1], hc, a1);
            a2 = FDOT2(w2[2][2 * c], ha, a2); a2 = FDOT2(w2[2][2 * c + 1], hc, a2);
            a3 = FDOT2(w2[3][2 * c], ha, a3); a3 = FDOT2(w2[3][2 * c + 1], hc, a3);
        }

        // ---- merge-reduce: fold 4 accs into 1 (2 stages), then 3 xor stages.
        // After: C(lane) = full dot of gate (ks&3) for this unit.
        float sA = (ks & 1) ? a0 : a1, kA = (ks & 1) ? a1 : a0;
        float A  = kA + __shfl_xor(sA, 1, 64);
        float sB = (ks & 1) ? a2 : a3, kB = (ks & 1) ? a3 : a2;
        float B  = kB + __shfl_xor(sB, 1, 64);
        float sC = (ks & 2) ? A : B,  kC = (ks & 2) ? B : A;
        float C  = kC + __shfl_xor(sC, 2, 64);
        C += __shfl_xor(C, 4, 64);
        C += __shfl_xor(C, 8, 64);
        C += __shfl_xor(C, 16, 64);
        // gather gates 1..3 into ks==0 (width-32 sub-group shuffles)
        const float Cf = __shfl(C, 1, 32);
        const float Cg = __shfl(C, 2, 32);
        const float Co = __shfl(C, 3, 32);

        // ---- LSTM cell in-lane (ks==0); gates exact-fp32 bias+gather ----
        if (ks == 0) {
            const float gi = sigmoidf_(C  + gx0 + b_i);
            const float gf = sigmoidf_(Cf + gx1 + b_f);
            const float gg = tanhf(Cg + gx2 + b_g);
            const float go = sigmoidf_(Co + gx3 + b_o);
            creg = gf * creg + gi * gg;
            const float hv = go * tanhf(creg);
            __hip_atomic_store(hs + (size_t)t * HH + unit, hv,
                               __ATOMIC_RELAXED, __HIP_MEMORY_SCOPE_AGENT);
        }
        // drain each wave's own h stores to the coherence point
        asm volatile("s_waitcnt vmcnt(0)" ::: "memory");
        __syncthreads();   // A: all 16 h stores visible; hl4 free to overwrite

        if (tid == 0)
            __hip_atomic_store(flags + (size_t)w * 16, (unsigned)(s + 1),
                               __ATOMIC_RELAXED, __HIP_MEMORY_SCOPE_AGENT);

        if (s + 1 < TT) {
            // fused poll+stage: thread p (<128) waits for producer p's flag,
            // then stages p's 16 h floats (one 64B line per thread).
            if (tid < NWGD) {
                unsigned* fl = flags + (size_t)tid * 16;
                while (__hip_atomic_load(fl, __ATOMIC_RELAXED,
                                         __HIP_MEMORY_SCOPE_AGENT)
                       < (unsigned)(s + 1)) {
                    __builtin_amdgcn_s_sleep(2);
                }
                asm volatile("" ::: "memory");
                const float* hsrc = hs + (size_t)t * HH + tid * 16;
                #pragma unroll
                for (int q = 0; q < 4; ++q) {
                    float4 hv;
                    hv.x = __hip_atomic_load(hsrc + 4 * q,     __ATOMIC_RELAXED, __HIP_MEMORY_SCOPE_AGENT);
                    hv.y = __hip_atomic_load(hsrc + 4 * q + 1, __ATOMIC_RELAXED, __HIP_MEMORY_SCOPE_AGENT);
                    hv.z = __hip_atomic_load(hsrc + 4 * q + 2, __ATOMIC_RELAXED, __HIP_MEMORY_SCOPE_AGENT);
                    hv.w = __hip_atomic_load(hsrc + 4 * q + 3, __ATOMIC_RELAXED, __HIP_MEMORY_SCOPE_AGENT);
                    const int f4i = tid * 4 + q;
                    hl4[f4i + (f4i >> 4)] = hv;
                }
            }
            __syncthreads();   // B: hlds ready for next dot
        }
    }
}

// out[t,v] = sum_j merged[t,j]*Wo[v,j] + bo[v],  merged = [hf | hb], K = 4096.
__global__ __launch_bounds__(256)
void out_gemm(const float* __restrict__ hsf, const float* __restrict__ hsb,
              const float* __restrict__ Wo, const float* __restrict__ bo,
              float* __restrict__ out)
{
    const int bn = blockIdx.x;
    const int bm = blockIdx.y;
    const int tid = threadIdx.x;
    const int tx = tid & 15, ty = tid >> 4;
    const int t0 = bm * 64, v0 = bn * 64;

    __shared__ float As[32][72];
    __shared__ float Bs[32][72];

    float acc[4][4] = {};

    const int rr = tid >> 2;
    const int kc = tid & 3;

    for (int kb = 0; kb < 2 * HH; kb += 32) {
        {
            const int k = kb + kc * 8;
            const float* asrc = (k < HH) ? (hsf + (size_t)(t0 + rr) * HH + k)
                                         : (hsb + (size_t)(t0 + rr) * HH + (k - HH));
            const float4 a0 = *reinterpret_cast<const float4*>(asrc);
            const float4 a1 = *reinterpret_cast<const float4*>(asrc + 4);
            const int kk = kc * 8;
            As[kk+0][rr]=a0.x; As[kk+1][rr]=a0.y; As[kk+2][rr]=a0.z; As[kk+3][rr]=a0.w;
            As[kk+4][rr]=a1.x; As[kk+5][rr]=a1.y; As[kk+6][rr]=a1.z; As[kk+7][rr]=a1.w;
            const float* bsrc = Wo + (size_t)(v0 + rr) * (2 * HH) + k;
            const float4 b0 = *reinterpret_cast<const float4*>(bsrc);
            const float4 b1 = *reinterpret_cast<const float4*>(bsrc + 4);
            Bs[kk+0][rr]=b0.x; Bs[kk+1][rr]=b0.y; Bs[kk+2][rr]=b0.z; Bs[kk+3][rr]=b0.w;
            Bs[kk+4][rr]=b1.x; Bs[kk+5][rr]=b1.y; Bs[kk+6][rr]=b1.z; Bs[kk+7][rr]=b1.w;
        }
        __syncthreads();
        #pragma unroll 8
        for (int kk = 0; kk < 32; ++kk) {
            const float4 av = *reinterpret_cast<const float4*>(&As[kk][ty * 4]);
            const float4 bv = *reinterpret_cast<const float4*>(&Bs[kk][tx * 4]);
            const float a[4] = {av.x, av.y, av.z, av.w};
            const float b[4] = {bv.x, bv.y, bv.z, bv.w};
            #pragma unroll
            for (int i2 = 0; i2 < 4; ++i2)
                #pragma unroll
                for (int j2 = 0; j2 < 4; ++j2)
                    acc[i2][j2] = fmaf(a[i2], b[j2], acc[i2][j2]);
        }
        __syncthreads();
    }
    #pragma unroll
    for (int i2 = 0; i2 < 4; ++i2) {
        const int t = t0 + ty * 4 + i2;
        #pragma unroll
        for (int j2 = 0; j2 < 4; ++j2) {
            const int v = v0 + tx * 4 + j2;
            out[(size_t)t * VV + v] = acc[i2][j2] + bo[v];
        }
    }
}

extern "C" void kernel_launch(void* const* d_in, const int* in_sizes, int n_in,
                              void* d_out, int out_size, void* d_ws, size_t ws_size,
                              hipStream_t stream)
{
    (void)in_sizes; (void)n_in; (void)out_size; (void)ws_size;

    const float* Wf  = (const float*)d_in[0];
    const float* bfv = (const float*)d_in[1];
    const float* Wb  = (const float*)d_in[2];
    const float* bbv = (const float*)d_in[3];
    const float* Wo  = (const float*)d_in[4];
    const float* bo  = (const float*)d_in[5];
    const int*   cid = (const int*)d_in[6];
    float* out = (float*)d_out;

    unsigned char* ws = (unsigned char*)d_ws;
    unsigned* bar = (unsigned*)ws;                         // 16 KiB flag area
    float* hsf = (float*)(ws + 65536);                     // [T][H] fp32, 16 MiB
    float* hsb = hsf + (size_t)TT * HH;                    // [T][H] fp32, 16 MiB

    // Re-zero flags every launch (ws poisoned once, never restored)
    (void)hipMemsetAsync(bar, 0, 16384, stream);

    lstm_kernel<<<dim3(2 * NWGD), dim3(BTH), 0, stream>>>(Wf, bfv, Wb, bbv, cid,
                                                          hsf, hsb, bar);
    out_gemm<<<dim3(VV / 64, TT / 64), dim3(256), 0, stream>>>(hsf, hsb, Wo, bo, out);
}

// Round 10
// 5710.491 us; speedup vs baseline: 2.0342x; 1.5729x over previous
//
#include <hip/hip_runtime.h>
#include <math.h>

// Problem dims
#define TT 2048
#define VV 1024
#define HH 2048
#define SS (VV + HH)        // 3072: row stride of Wf_w / Wb_w

// Geometry: 256 WGs x 512 threads, one WG per CU (forced by LDS pad).
#define NWGD 128            // workgroups per direction
#define BTH  512            // threads per workgroup (8 waves = 2/EU)
#define UPW  16             // hidden units per wg
#define KSL  32             // k-slices per unit
#define KPT  64             // k-elements per thread (per gate row)

static_assert(NWGD * UPW == HH, "unit coverage");
static_assert(UPW * KSL == BTH, "thread coverage");
static_assert(KSL * KPT == HH, "k coverage");

typedef _Float16 half2_t __attribute__((ext_vector_type(2)));
typedef unsigned uint4v  __attribute__((ext_vector_type(4)));

#if defined(__has_builtin)
#if __has_builtin(__builtin_amdgcn_fdot2)
#define FDOT2(w, h, c) __builtin_amdgcn_fdot2((w), (h), (c), false)
#endif
#endif
#ifndef FDOT2
__device__ __forceinline__ float fdot2_asm(half2_t w, half2_t h, float c) {
    float r = c;
    asm volatile("v_dot2_f32_f16 %0, %1, %2, %0" : "+v"(r) : "v"(w), "v"(h));
    return r;
}
#define FDOT2(w, h, c) fdot2_asm((w), (h), (c))
#endif

__device__ __forceinline__ float sigmoidf_(float x) {
    return 1.0f / (1.0f + __expf(-x));
}

// Mailbox: [dir][parity][producer p<128][quad q<4] of 16B:
//   { h(4q..4q+3) as 4 x fp16 in w0,w1 ; 0 ; tag = s+1 }
// One dwordx4 = data + validity in a single L3 transaction.

__global__ __launch_bounds__(BTH) __attribute__((amdgpu_waves_per_eu(2, 2)))
void lstm_kernel(const float* __restrict__ Wf, const float* __restrict__ bfv,
                 const float* __restrict__ Wb, const float* __restrict__ bbv,
                 const int* __restrict__ cidx,
                 float* __restrict__ hsf, float* __restrict__ hsb,
                 unsigned* __restrict__ mbx)
{
    const int wg   = blockIdx.x;
    const int dir  = wg >> 7;            // 0 fwd, 1 bwd
    const int w    = wg & (NWGD - 1);
    const int tid  = threadIdx.x;
    const int rg   = tid >> 5;           // unit_local 0..15
    const int ks   = tid & (KSL - 1);    // k-slice 0..31
    const int unit = w * UPW + rg;

    const float* W    = dir ? Wb : Wf;
    const float* bias = dir ? bbv : bfv;
    float* hs         = dir ? hsb : hsf;
    unsigned* mbd     = mbx + (size_t)dir * (2 * NWGD * 16);  // u32 units

    // h in LDS as fp16, rows of 68 ushorts (136B): ds_read_b64 2-way max.
    __shared__ unsigned long long hl2_u64[(KSL * 68) / 4];    // 4352 B
    __shared__ ushort hstage[UPW];
    // Force 1 WG/CU (all 256 WGs co-resident across 256 CUs).
    __shared__ char force_one_wg[100 * 1024];
    if (tid == 0) ((volatile char*)force_one_wg)[0] = 0;
    ushort* hl2 = (ushort*)hl2_u64;

    // ---- one-time: weight slab -> 128 packed-fp16 VGPRs (4 gates x 32 half2)
    half2_t w2[4][KPT / 2];
    #pragma unroll
    for (int j = 0; j < 4; ++j) {
        const float* rbase = W + (size_t)(j * HH + unit) * SS + VV + ks * KPT;
        #pragma unroll
        for (int q = 0; q < KPT / 4; ++q) {
            const float4 wv = *reinterpret_cast<const float4*>(rbase + 4 * q);
            w2[j][2 * q]     = half2_t{(_Float16)wv.x, (_Float16)wv.y};
            w2[j][2 * q + 1] = half2_t{(_Float16)wv.z, (_Float16)wv.w};
        }
    }
    const float b_i = bias[0 * HH + unit];
    const float b_f = bias[1 * HH + unit];
    const float b_g = bias[2 * HH + unit];
    const float b_o = bias[3 * HH + unit];
    float creg = 0.0f;                                    // cell state (ks==0)

    // prestage h=0 for step 0
    for (int i = tid; i < (KSL * 68) / 4; i += BTH) hl2_u64[i] = 0ull;
    __syncthreads();

    for (int s = 0; s < TT; ++s) {
        const int t  = dir ? (TT - 1 - s) : s;
        const int xt = cidx[t];
        // one-hot input projection: exact fp32 gather (ks==0 lanes only)
        float gx0 = 0.f, gx1 = 0.f, gx2 = 0.f, gx3 = 0.f;
        if (ks == 0) {
            gx0 = W[(size_t)(0 * HH + unit) * SS + xt];
            gx1 = W[(size_t)(1 * HH + unit) * SS + xt];
            gx2 = W[(size_t)(2 * HH + unit) * SS + xt];
            gx3 = W[(size_t)(3 * HH + unit) * SS + xt];
        }

        // ---- recurrent dot: 4 gates x 64 k, fp16 h from LDS (b64 reads) ----
        float a0 = 0.f, a1 = 0.f, a2 = 0.f, a3 = 0.f;
        const ushort* hrow = hl2 + ks * 68;
        #pragma unroll
        for (int c = 0; c < KPT / 4; ++c) {
            const unsigned long long hv8 =
                *reinterpret_cast<const unsigned long long*>(hrow + c * 4);
            const half2_t ha = __builtin_bit_cast(half2_t, (unsigned)hv8);
            const half2_t hc = __builtin_bit_cast(half2_t, (unsigned)(hv8 >> 32));
            a0 = FDOT2(w2[0][2 * c], ha, a0); a0 = FDOT2(w2[0][2 * c + 1], hc, a0);
            a1 = FDOT2(w2[1][2 * c], ha, a1); a1 = FDOT2(w2[1][2 * c + 1], hc, a1);
            a2 = FDOT2(w2[2][2 * c], ha, a2); a2 = FDOT2(w2[2][2 * c + 1], hc, a2);
            a3 = FDOT2(w2[3][2 * c], ha, a3); a3 = FDOT2(w2[3][2 * c + 1], hc, a3);
        }

        // ---- merge-reduce: fold 4 accs into 1 (2 stages), then 3 xor stages.
        float sA = (ks & 1) ? a0 : a1, kA = (ks & 1) ? a1 : a0;
        float A  = kA + __shfl_xor(sA, 1, 64);
        float sB = (ks & 1) ? a2 : a3, kB = (ks & 1) ? a3 : a2;
        float B  = kB + __shfl_xor(sB, 1, 64);
        float sC = (ks & 2) ? A : B,  kC = (ks & 2) ? B : A;
        float C  = kC + __shfl_xor(sC, 2, 64);
        C += __shfl_xor(C, 4, 64);
        C += __shfl_xor(C, 8, 64);
        C += __shfl_xor(C, 16, 64);
        const float Cf = __shfl(C, 1, 32);
        const float Cg = __shfl(C, 2, 32);
        const float Co = __shfl(C, 3, 32);

        // ---- LSTM cell in-lane (ks==0): h -> hs (plain) + hstage (fp16) ----
        if (ks == 0) {
            const float gi = sigmoidf_(C  + gx0 + b_i);
            const float gf = sigmoidf_(Cf + gx1 + b_f);
            const float gg = tanhf(Cg + gx2 + b_g);
            const float go = sigmoidf_(Co + gx3 + b_o);
            creg = gf * creg + gi * gg;
            const float hv = go * tanhf(creg);
            hs[(size_t)t * HH + unit] = hv;               // for out_gemm
            hstage[rg] = __builtin_bit_cast(ushort, (_Float16)hv);
        }
        __syncthreads();   // A: dot-reads of hl2 done; hstage populated

        // ---- publish: 4 packer threads, one tagged dwordx4 each ----
        if (tid < 4) {
            const unsigned w0 = (unsigned)hstage[4 * tid] |
                                ((unsigned)hstage[4 * tid + 1] << 16);
            const unsigned w1 = (unsigned)hstage[4 * tid + 2] |
                                ((unsigned)hstage[4 * tid + 3] << 16);
            const uint4v pv = {w0, w1, 0u, (unsigned)(s + 1)};
            unsigned* dst = mbd + (size_t)(s & 1) * (NWGD * 16) + w * 16 + tid * 4;
            asm volatile("global_store_dwordx4 %0, %1, off sc0 sc1"
                         :: "v"(dst), "v"(pv) : "memory");
        }

        if (s + 1 < TT) {
            // ---- poll+stage: thread tid owns producer tid>>2, quad tid&3 ----
            const unsigned tag = (unsigned)(s + 1);
            const unsigned* src = mbd + (size_t)(s & 1) * (NWGD * 16)
                                + (tid >> 2) * 16 + (tid & 3) * 4;
            uint4v v;
            for (;;) {
                asm volatile("global_load_dwordx4 %0, %1, off sc0 sc1\n\t"
                             "s_waitcnt vmcnt(0)"
                             : "=&v"(v) : "v"(src) : "memory");
                if (v.w == tag) break;
                __builtin_amdgcn_s_sleep(2);
            }
            const unsigned long long hv8 =
                (unsigned long long)v.x | ((unsigned long long)v.y << 32);
            // k0 = 4*tid: row = tid>>4, col(ushort) = (tid&15)*4
            *reinterpret_cast<unsigned long long*>(
                hl2 + (tid >> 4) * 68 + (tid & 15) * 4) = hv8;
            __syncthreads();   // B: hl2 ready for next dot
        }
    }
}

// out[t,v] = sum_j merged[t,j]*Wo[v,j] + bo[v],  merged = [hf | hb], K = 4096.
__global__ __launch_bounds__(256)
void out_gemm(const float* __restrict__ hsf, const float* __restrict__ hsb,
              const float* __restrict__ Wo, const float* __restrict__ bo,
              float* __restrict__ out)
{
    const int bn = blockIdx.x;
    const int bm = blockIdx.y;
    const int tid = threadIdx.x;
    const int tx = tid & 15, ty = tid >> 4;
    const int t0 = bm * 64, v0 = bn * 64;

    __shared__ float As[32][72];
    __shared__ float Bs[32][72];

    float acc[4][4] = {};

    const int rr = tid >> 2;
    const int kc = tid & 3;

    for (int kb = 0; kb < 2 * HH; kb += 32) {
        {
            const int k = kb + kc * 8;
            const float* asrc = (k < HH) ? (hsf + (size_t)(t0 + rr) * HH + k)
                                         : (hsb + (size_t)(t0 + rr) * HH + (k - HH));
            const float4 a0 = *reinterpret_cast<const float4*>(asrc);
            const float4 a1 = *reinterpret_cast<const float4*>(asrc + 4);
            const int kk = kc * 8;
            As[kk+0][rr]=a0.x; As[kk+1][rr]=a0.y; As[kk+2][rr]=a0.z; As[kk+3][rr]=a0.w;
            As[kk+4][rr]=a1.x; As[kk+5][rr]=a1.y; As[kk+6][rr]=a1.z; As[kk+7][rr]=a1.w;
            const float* bsrc = Wo + (size_t)(v0 + rr) * (2 * HH) + k;
            const float4 b0 = *reinterpret_cast<const float4*>(bsrc);
            const float4 b1 = *reinterpret_cast<const float4*>(bsrc + 4);
            Bs[kk+0][rr]=b0.x; Bs[kk+1][rr]=b0.y; Bs[kk+2][rr]=b0.z; Bs[kk+3][rr]=b0.w;
            Bs[kk+4][rr]=b1.x; Bs[kk+5][rr]=b1.y; Bs[kk+6][rr]=b1.z; Bs[kk+7][rr]=b1.w;
        }
        __syncthreads();
        #pragma unroll 8
        for (int kk = 0; kk < 32; ++kk) {
            const float4 av = *reinterpret_cast<const float4*>(&As[kk][ty * 4]);
            const float4 bv = *reinterpret_cast<const float4*>(&Bs[kk][tx * 4]);
            const float a[4] = {av.x, av.y, av.z, av.w};
            const float b[4] = {bv.x, bv.y, bv.z, bv.w};
            #pragma unroll
            for (int i2 = 0; i2 < 4; ++i2)
                #pragma unroll
                for (int j2 = 0; j2 < 4; ++j2)
                    acc[i2][j2] = fmaf(a[i2], b[j2], acc[i2][j2]);
        }
        __syncthreads();
    }
    #pragma unroll
    for (int i2 = 0; i2 < 4; ++i2) {
        const int t = t0 + ty * 4 + i2;
        #pragma unroll
        for (int j2 = 0; j2 < 4; ++j2) {
            const int v = v0 + tx * 4 + j2;
            out[(size_t)t * VV + v] = acc[i2][j2] + bo[v];
        }
    }
}

extern "C" void kernel_launch(void* const* d_in, const int* in_sizes, int n_in,
                              void* d_out, int out_size, void* d_ws, size_t ws_size,
                              hipStream_t stream)
{
    (void)in_sizes; (void)n_in; (void)out_size; (void)ws_size;

    const float* Wf  = (const float*)d_in[0];
    const float* bfv = (const float*)d_in[1];
    const float* Wb  = (const float*)d_in[2];
    const float* bbv = (const float*)d_in[3];
    const float* Wo  = (const float*)d_in[4];
    const float* bo  = (const float*)d_in[5];
    const int*   cid = (const int*)d_in[6];
    float* out = (float*)d_out;

    unsigned char* ws = (unsigned char*)d_ws;
    unsigned* mbx = (unsigned*)ws;                         // 32 KiB mailbox
    float* hsf = (float*)(ws + 65536);                     // [T][H] fp32, 16 MiB
    float* hsb = hsf + (size_t)TT * HH;                    // [T][H] fp32, 16 MiB

    // Re-zero mailbox tags every launch (ws poisoned once, never restored)
    (void)hipMemsetAsync(mbx, 0, 32768, stream);

    lstm_kernel<<<dim3(2 * NWGD), dim3(BTH), 0, stream>>>(Wf, bfv, Wb, bbv, cid,
                                                          hsf, hsb, mbx);
    out_gemm<<<dim3(VV / 64, TT / 64), dim3(256), 0, stream>>>(hsf, hsb, Wo, bo, out);
}